// Round 5
// baseline (149.770 us; speedup 1.0000x reference)
//
#include <hip/hip_runtime.h>
#include <hip/hip_bf16.h>

// GQA forward, MI355X. prep (cast+transpose fused) -> fused QKV GEMM (128^2,
// counted-vmcnt dbuf) -> V^T transpose -> flash attention (group-shared K/V:
// 4 waves = 4 heads of one KV group; 2 chains/wave; counted-vmcnt 2-deep
// pipeline, raw barriers; exp2 softmax + defer-max) -> out GEMM + bias.

typedef __attribute__((ext_vector_type(8))) short          bf16x8;
typedef __attribute__((ext_vector_type(4))) float          f32x4;
typedef __attribute__((ext_vector_type(4))) unsigned short u16x4;
typedef __attribute__((ext_vector_type(8))) unsigned short u16x8;

#define DEV __device__ __forceinline__

static constexpr int BB   = 2;
static constexpr int SS   = 2048;
static constexpr int EMB  = 1024;
static constexpr int QKVD = 1536;   // Q(1024) | K(256) | V(256) fused output
static constexpr float SC2 = 0.18033688011112042f;  // 0.125 * log2(e)

DEV unsigned short f2b(float f) {
  union { float f; unsigned u; } v; v.f = f;
  unsigned r = (v.u + 0x7FFFu + ((v.u >> 16) & 1u)) >> 16;  // RNE
  return (unsigned short)r;
}

DEV unsigned packbf2(float a, float b) {
  __hip_bfloat162 h = __float22bfloat162_rn(make_float2(a, b));
  union { __hip_bfloat162 h; unsigned u; } c; c.h = h; return c.u;
}

DEV void gl_lds16(const void* g, void* l) {
  __builtin_amdgcn_global_load_lds((__attribute__((address_space(1))) void*)g,
                                   (__attribute__((address_space(3))) void*)l,
                                   16, 0, 0);
}

// ---------------- prep: x cast (blocks 0..2047) + weight transposes --------
__global__ __launch_bounds__(256) void prep_kernel(const float* __restrict__ x,
                                                   unsigned short* __restrict__ xb,
                                                   const float* __restrict__ Wq,
                                                   const float* __restrict__ Wk,
                                                   const float* __restrict__ Wv,
                                                   const float* __restrict__ Wo,
                                                   unsigned short* __restrict__ Wqkv_t,
                                                   unsigned short* __restrict__ Wo_t) {
  __shared__ unsigned short tile[64][72];
  const int blk = blockIdx.x;
  const int tid = threadIdx.x;
  if (blk < 2048) {
    size_t i = ((size_t)blk * 256 + tid) * 8;
    f32x4 f0 = *(const f32x4*)(x + i);
    f32x4 f1 = *(const f32x4*)(x + i + 4);
    u16x8 o;
    o[0] = f2b(f0[0]); o[1] = f2b(f0[1]); o[2] = f2b(f0[2]); o[3] = f2b(f0[3]);
    o[4] = f2b(f1[0]); o[5] = f2b(f1[1]); o[6] = f2b(f1[2]); o[7] = f2b(f1[3]);
    *(u16x8*)(xb + i) = o;
    return;
  }
  int idx = blk - 2048;
  const float* W; unsigned short* Dst; int N, kb, nb;
  if (idx < 256)      { W = Wq; Dst = Wqkv_t;                       N = 1024; kb = idx >> 4; nb = idx & 15; }
  else if (idx < 320) { int j = idx - 256; W = Wk; Dst = Wqkv_t + (size_t)1024 * 1024; N = 256; kb = j >> 2; nb = j & 3; }
  else if (idx < 384) { int j = idx - 320; W = Wv; Dst = Wqkv_t + (size_t)1280 * 1024; N = 256; kb = j >> 2; nb = j & 3; }
  else                { int j = idx - 384; W = Wo; Dst = Wo_t;      N = 1024; kb = j >> 4; nb = j & 15; }
  const int kb64 = kb * 64, nb64 = nb * 64;
#pragma unroll
  for (int p = 0; p < 16; ++p) {
    int i = tid + 256 * p;
    int k = i >> 6, n = i & 63;
    tile[k][n] = f2b(W[(size_t)(kb64 + k) * N + nb64 + n]);
  }
  __syncthreads();
#pragma unroll
  for (int p = 0; p < 16; ++p) {
    int i = tid + 256 * p;
    int n = i >> 6, k = i & 63;
    Dst[(size_t)(nb64 + n) * 1024 + kb64 + k] = tile[k][n];
  }
}

// ---------------- V^T: QKV cols [1280..1536) -> Vt[bg=b*4+g][d=64][s=2048] --
__global__ __launch_bounds__(256) void transpose_v(const unsigned short* __restrict__ QKV,
                                                   unsigned short* __restrict__ Vt) {
  __shared__ unsigned short t[64][72];
  const int s0 = blockIdx.x * 64;
  const int bg = blockIdx.y;
  const int b = bg >> 2, g = bg & 3;
  const int tid = threadIdx.x;
#pragma unroll
  for (int p = 0; p < 2; ++p) {
    int i = tid + 256 * p;
    int si = i >> 3, d0 = (i & 7) * 8;
    bf16x8 v = *(const bf16x8*)(QKV + ((size_t)(b * SS + s0 + si)) * QKVD + 1280 + g * 64 + d0);
#pragma unroll
    for (int j = 0; j < 8; ++j) t[si][d0 + j] = (unsigned short)v[j];
  }
  __syncthreads();
#pragma unroll
  for (int p = 0; p < 2; ++p) {
    int i = tid + 256 * p;
    int d = i >> 3, sv = (i & 7) * 8;
    bf16x8 vv;
#pragma unroll
    for (int j = 0; j < 8; ++j) vv[j] = (short)t[sv + j][d];
    *(bf16x8*)(Vt + ((size_t)(bg * 64 + d)) * SS + s0 + sv) = vv;
  }
}

// ---------------- GEMM: C[M,Nc] = A[M,K] * Bt[Nc,K]^T, 128x128 tile --------
// 4 waves (2x2), wave = 64x64 (4x4 frags). Counted-vmcnt double-buffer:
// stage t+2 after readers-done barrier; vmcnt(4) = previous tile resident.
template <bool BF16_OUT, bool BIAS>
__global__ __launch_bounds__(256) void gemm128(const unsigned short* __restrict__ A,
                                               const unsigned short* __restrict__ Bt,
                                               void* __restrict__ Cv,
                                               const float* __restrict__ bias,
                                               int Nc, int Kd) {
  const int tid = threadIdx.x;
  const int w = tid >> 6, lane = tid & 63;
  const int l15 = lane & 15, l4 = lane >> 4;
  const int wr = w >> 1, wc = w & 1;
  const size_t rb = (size_t)blockIdx.x * 128;
  const size_t cb = (size_t)blockIdx.y * 128;

  __shared__ alignas(16) unsigned short sA[2][128 * 32];
  __shared__ alignas(16) unsigned short sB[2][128 * 32];

  f32x4 acc[4][4] = {};

  const unsigned short* Ap = A + (rb + 32 * w + (lane >> 2)) * (size_t)Kd + (lane & 3) * 8;
  const unsigned short* Bp = Bt + (cb + 32 * w + (lane >> 2)) * (size_t)Kd + (lane & 3) * 8;

  auto STAGE = [&](int kt, int bsel) {
    const size_t off = (size_t)kt * 32;
    gl_lds16(Ap + off,                    &sA[bsel][1024 * w]);
    gl_lds16(Ap + off + 16 * (size_t)Kd, &sA[bsel][1024 * w + 512]);
    gl_lds16(Bp + off,                    &sB[bsel][1024 * w]);
    gl_lds16(Bp + off + 16 * (size_t)Kd, &sB[bsel][1024 * w + 512]);
  };

  const int KT = Kd >> 5;
  STAGE(0, 0);
  STAGE(1, 1);
  asm volatile("s_waitcnt vmcnt(4)" ::: "memory");
  __builtin_amdgcn_s_barrier();

  for (int kt = 0; kt < KT; ++kt) {
    const int cur = kt & 1;
    bf16x8 af[4], bfr[4];
#pragma unroll
    for (int m = 0; m < 4; ++m)
      af[m] = *(const bf16x8*)&sA[cur][(wr * 64 + m * 16 + l15) * 32 + 8 * l4];
#pragma unroll
    for (int n = 0; n < 4; ++n)
      bfr[n] = *(const bf16x8*)&sB[cur][(wc * 64 + n * 16 + l15) * 32 + 8 * l4];
#pragma unroll
    for (int m = 0; m < 4; ++m)
#pragma unroll
      for (int n = 0; n < 4; ++n)
        acc[m][n] = __builtin_amdgcn_mfma_f32_16x16x32_bf16(af[m], bfr[n], acc[m][n], 0, 0, 0);

    __builtin_amdgcn_s_barrier();          // all waves done reading buf[cur]
    if (kt + 2 < KT) {
      STAGE(kt + 2, cur);
      asm volatile("s_waitcnt vmcnt(4)" ::: "memory");
    } else {
      asm volatile("s_waitcnt vmcnt(0)" ::: "memory");
    }
    __builtin_amdgcn_s_barrier();          // tile kt+1 resident for everyone
  }

#pragma unroll
  for (int m = 0; m < 4; ++m)
#pragma unroll
    for (int n = 0; n < 4; ++n) {
      float bv = 0.f;
      if constexpr (BIAS) bv = bias[cb + wc * 64 + n * 16 + l15];
#pragma unroll
      for (int r = 0; r < 4; ++r) {
        size_t row = rb + wr * 64 + m * 16 + 4 * l4 + r;
        size_t col = cb + wc * 64 + n * 16 + l15;
        if constexpr (BF16_OUT)
          ((unsigned short*)Cv)[row * Nc + col] = f2b(acc[m][n][r]);
        else
          ((float*)Cv)[row * Nc + col] = acc[m][n][r] + bv;
      }
    }
}

// ---------------- flash attention -----------------------------------------
struct QS {
  bf16x8 qf0, qf1;
  f32x4 o[4];
  float m2, l;
  int qg;
};

DEV void qs_init(QS& s, const unsigned short* __restrict__ QKV,
                 int b, int h, int row0, int l15, int l4) {
  s.qg = row0 + l15;
  const unsigned short* qp =
      QKV + ((size_t)(b * SS + row0 + l15)) * QKVD + h * 64 + 8 * l4;
  s.qf0 = *(const bf16x8*)qp;
  s.qf1 = *(const bf16x8*)(qp + 32);
#pragma unroll
  for (int t = 0; t < 4; ++t) s.o[t] = f32x4{0.f, 0.f, 0.f, 0.f};
  s.m2 = -3e38f;
  s.l = 0.f;
}

DEV void qs_tile(QS& st, const unsigned short* __restrict__ sKc,
                 const unsigned short* __restrict__ sVc,
                 int kv0, bool masked,
                 int l15, int l4, int xsw, int s0, int s1, bool hi) {
  // S^T = (K Q^T): lane gets S[q=l15][kv0+16c+4*l4+r]
  f32x4 p[4];
  __builtin_amdgcn_s_setprio(1);
#pragma unroll
  for (int c = 0; c < 4; ++c) {
    const unsigned short* krow = &sKc[(c * 16 + l15) * 64];
    bf16x8 kf0 = *(const bf16x8*)&krow[(l4 ^ xsw) * 8];
    bf16x8 kf1 = *(const bf16x8*)&krow[((4 | l4) ^ xsw) * 8];
    f32x4 z = {0.f, 0.f, 0.f, 0.f};
    z = __builtin_amdgcn_mfma_f32_16x16x32_bf16(kf0, st.qf0, z, 0, 0, 0);
    z = __builtin_amdgcn_mfma_f32_16x16x32_bf16(kf1, st.qf1, z, 0, 0, 0);
    p[c] = z;
  }
  __builtin_amdgcn_s_setprio(0);

  if (masked) {
#pragma unroll
    for (int c = 0; c < 4; ++c)
#pragma unroll
      for (int r = 0; r < 4; ++r) {
        int kv = kv0 + c * 16 + 4 * l4 + r;
        if (kv > st.qg) p[c][r] = -3e38f;
      }
  }

  float mx = -3e38f;
#pragma unroll
  for (int c = 0; c < 4; ++c)
#pragma unroll
    for (int r = 0; r < 4; ++r) mx = fmaxf(mx, p[c][r]);
  mx = fmaxf(mx, __shfl_xor(mx, 16));
  mx = fmaxf(mx, __shfl_xor(mx, 32));
  float mx2 = mx * SC2;

  if (!__all(mx2 <= st.m2 + 8.f)) {      // defer-max (T13)
    float mn = fmaxf(st.m2, mx2);
    float corr = exp2f(st.m2 - mn);
    st.m2 = mn;
    st.l *= corr;
    f32x4 cf;
#pragma unroll
    for (int r = 0; r < 4; ++r) cf[r] = __shfl(corr, 4 * l4 + r);
#pragma unroll
    for (int t = 0; t < 4; ++t)
#pragma unroll
      for (int r = 0; r < 4; ++r) st.o[t][r] *= cf[r];
  }

  float rs = 0.f;
  unsigned w0[4], w1[4];
#pragma unroll
  for (int c = 0; c < 4; ++c) {
    float e0 = exp2f(fmaf(p[c][0], SC2, -st.m2));
    float e1 = exp2f(fmaf(p[c][1], SC2, -st.m2));
    float e2 = exp2f(fmaf(p[c][2], SC2, -st.m2));
    float e3 = exp2f(fmaf(p[c][3], SC2, -st.m2));
    rs += (e0 + e1) + (e2 + e3);
    w0[c] = packbf2(e0, e1);
    w1[c] = packbf2(e2, e3);
  }
  rs += __shfl_xor(rs, 16);
  rs += __shfl_xor(rs, 32);
  st.l += rs;

  // P relayout (dest lane (l15,l4),ks gets P[q=l15][32ks+8*l4+j]) + PV
#pragma unroll
  for (int ks = 0; ks < 2; ++ks) {
    unsigned a00 = __shfl(w0[2 * ks], s0), a01 = __shfl(w0[2 * ks + 1], s0);
    unsigned a10 = __shfl(w1[2 * ks], s0), a11 = __shfl(w1[2 * ks + 1], s0);
    unsigned b00 = __shfl(w0[2 * ks], s1), b01 = __shfl(w0[2 * ks + 1], s1);
    unsigned b10 = __shfl(w1[2 * ks], s1), b11 = __shfl(w1[2 * ks + 1], s1);
    union { bf16x8 v; unsigned u[4]; } pf;
    pf.u[0] = hi ? a01 : a00;
    pf.u[1] = hi ? a11 : a10;
    pf.u[2] = hi ? b01 : b00;
    pf.u[3] = hi ? b11 : b10;
    __builtin_amdgcn_s_setprio(1);
#pragma unroll
    for (int t = 0; t < 4; ++t) {
      const unsigned short* vrow = &sVc[(t * 16 + l15) * 64];
      bf16x8 vf = *(const bf16x8*)&vrow[((4 * ks + l4) ^ xsw) * 8];
      st.o[t] = __builtin_amdgcn_mfma_f32_16x16x32_bf16(pf.v, vf, st.o[t], 0, 0, 0);
    }
    __builtin_amdgcn_s_setprio(0);
  }
}

DEV void qs_write(const QS& st, unsigned short* __restrict__ Ctx,
                  int b, int h, int row0, int l15, int l4) {
  f32x4 lf;
#pragma unroll
  for (int r = 0; r < 4; ++r) lf[r] = __shfl(st.l, 4 * l4 + r);
#pragma unroll
  for (int t = 0; t < 4; ++t)
#pragma unroll
    for (int r = 0; r < 4; ++r) {
      Ctx[((size_t)(b * SS + row0 + 4 * l4 + r)) * 1024 + h * 64 + t * 16 + l15] =
          f2b(st.o[t][r] / lf[r]);
    }
}

// Block f (512): xcd=f&7 -> (b,g); k=f>>3 in [0,32); qt2 = f<256 ? 63-k : k
// (per-CU pair sums to 33 rounds exactly; long blocks dispatch first).
// 4 waves = 4 heads of group g, sharing staged K/V; each wave runs 2
// independent 16-row chains. Counted-vmcnt 2-deep pipeline, raw barriers.
__global__ __launch_bounds__(256) void attn_kernel(const unsigned short* __restrict__ QKV,
                                                   const unsigned short* __restrict__ Vt,
                                                   unsigned short* __restrict__ Ctx) {
  const int f = blockIdx.x;
  const int xcd = f & 7;
  const int b = xcd >> 2, g = xcd & 3;
  const int k8 = (f >> 3) & 31;
  const int qt2 = (f < 256) ? (63 - k8) : k8;
  const int nkv = (qt2 >> 1) + 1;

  const int tid = threadIdx.x;
  const int w = tid >> 6, lane = tid & 63;
  const int l15 = lane & 15, l4 = lane >> 4;
  const int h = g * 4 + w;
  const int qbase = qt2 * 32;

  __shared__ alignas(16) unsigned short sK[2][64 * 64];
  __shared__ alignas(16) unsigned short sV[2][64 * 64];

  QS A, B;
  qs_init(A, QKV, b, h, qbase, l15, l4);
  qs_init(B, QKV, b, h, qbase + 16, l15, l4);

  // staging: LDS[row][c] = G[row][c ^ (row&7)] (16B chunks)
  const int srow = tid >> 3;
  const int sc   = tid & 7;
  const unsigned short* kstage0 =
      QKV + ((size_t)(b * SS + srow)) * QKVD + 1024 + g * 64 + (sc ^ (srow & 7)) * 8;
  const unsigned short* kstage1 =
      QKV + ((size_t)(b * SS + srow + 32)) * QKVD + 1024 + g * 64 + (sc ^ ((srow + 32) & 7)) * 8;
  const unsigned short* vstage0 =
      Vt + ((size_t)(((b << 2) | g) * 64 + srow)) * SS + (sc ^ (srow & 7)) * 8;
  const unsigned short* vstage1 =
      Vt + ((size_t)(((b << 2) | g) * 64 + srow + 32)) * SS + (sc ^ ((srow + 32) & 7)) * 8;

  const int xsw = (l15 & 7);
  const int s0 = l15 | (((2 * l4) & 3) << 4);
  const int s1 = l15 | (((2 * l4 + 1) & 3) << 4);
  const bool hi = (l4 >= 2);

  {
    char* kb0 = (char*)&sK[0][0] + (w << 10);
    char* vb0 = (char*)&sV[0][0] + (w << 10);
    gl_lds16(kstage0, kb0);
    gl_lds16(kstage1, kb0 + 4096);
    gl_lds16(vstage0, vb0);
    gl_lds16(vstage1, vb0 + 4096);
  }
  if (nkv > 1) {
    char* kb1 = (char*)&sK[1][0] + (w << 10);
    char* vb1 = (char*)&sV[1][0] + (w << 10);
    const size_t ko = (size_t)64 * QKVD;
    gl_lds16(kstage0 + ko, kb1);
    gl_lds16(kstage1 + ko, kb1 + 4096);
    gl_lds16(vstage0 + 64, vb1);
    gl_lds16(vstage1 + 64, vb1 + 4096);
    asm volatile("s_waitcnt vmcnt(4)" ::: "memory");
  } else {
    asm volatile("s_waitcnt vmcnt(0)" ::: "memory");
  }
  __builtin_amdgcn_s_barrier();

  for (int kt = 0; kt < nkv; ++kt) {
    const int cur = kt & 1;
    const int kv0 = kt * 64;
    const bool masked = (kt == nkv - 1);

    qs_tile(A, &sK[cur][0], &sV[cur][0], kv0, masked, l15, l4, xsw, s0, s1, hi);
    qs_tile(B, &sK[cur][0], &sV[cur][0], kv0, masked, l15, l4, xsw, s0, s1, hi);

    __builtin_amdgcn_s_barrier();          // all waves done reading buf[cur]
    if (kt + 2 < nkv) {
      const size_t ko = (size_t)(kv0 + 128) * QKVD;
      char* kb = (char*)&sK[cur][0] + (w << 10);
      char* vb = (char*)&sV[cur][0] + (w << 10);
      gl_lds16(kstage0 + ko, kb);
      gl_lds16(kstage1 + ko, kb + 4096);
      gl_lds16(vstage0 + kv0 + 128, vb);
      gl_lds16(vstage1 + kv0 + 128, vb + 4096);
      asm volatile("s_waitcnt vmcnt(4)" ::: "memory");
    } else {
      asm volatile("s_waitcnt vmcnt(0)" ::: "memory");
    }
    __builtin_amdgcn_s_barrier();          // tile kt+1 resident for everyone
  }

  qs_write(A, Ctx, b, h, qbase, l15, l4);
  qs_write(B, Ctx, b, h, qbase + 16, l15, l4);
}

// ---------------------------------------------------------------------------
extern "C" void kernel_launch(void* const* d_in, const int* in_sizes, int n_in,
                              void* d_out, int out_size, void* d_ws, size_t ws_size,
                              hipStream_t stream) {
  (void)in_sizes; (void)n_in; (void)out_size; (void)ws_size;
  const float* x  = (const float*)d_in[0];
  const float* Wq = (const float*)d_in[1];
  const float* Wk = (const float*)d_in[2];
  const float* Wv = (const float*)d_in[3];
  const float* Wo = (const float*)d_in[4];
  const float* bo = (const float*)d_in[5];
  float* out = (float*)d_out;

  char* ws = (char*)d_ws;
  unsigned short* x_bf   = (unsigned short*)(ws);                        // 8 MiB (aliased w/ Ctx)
  unsigned short* Ctx    = (unsigned short*)(ws);                        // 8 MiB
  unsigned short* QKVb   = (unsigned short*)(ws + (size_t)( 8u << 20));  // 12 MiB
  unsigned short* Wqkv_t = (unsigned short*)(ws + (size_t)(20u << 20));  // 3 MiB
  unsigned short* Wo_t   = (unsigned short*)(ws + (size_t)(23u << 20));  // 2 MiB
  unsigned short* Vtb    = (unsigned short*)(ws + (size_t)(25u << 20));  // 2 MiB

  prep_kernel<<<dim3(2688), 256, 0, stream>>>(x, x_bf, Wq, Wk, Wv, Wo, Wqkv_t, Wo_t);

  gemm128<true, false><<<dim3(32, 12), 256, 0, stream>>>(
      x_bf, Wqkv_t, QKVb, nullptr, QKVD, EMB);

  transpose_v<<<dim3(32, 8), 256, 0, stream>>>(QKVb, Vtb);

  attn_kernel<<<dim3(512), 256, 0, stream>>>(QKVb, Vtb, Ctx);

  gemm128<false, true><<<dim3(32, 8), 256, 0, stream>>>(
      Ctx, Wo_t, out, bo, EMB, EMB);
}

// Round 6
// 123.100 us; speedup vs baseline: 1.2166x; 1.2166x over previous
//
#include <hip/hip_runtime.h>
#include <hip/hip_bf16.h>

// GQA forward, MI355X. prep (cast+transpose fused) -> fused QKV GEMM (128^2,
// counted-vmcnt dbuf) -> V^T transpose -> flash attention (intra-block
// complementary q-tile pairs: every block = 33 tile-calls; counted-vmcnt
// 2-deep pipeline, raw barriers; exp2 softmax + defer-max) -> out GEMM + bias.

typedef __attribute__((ext_vector_type(8))) short          bf16x8;
typedef __attribute__((ext_vector_type(4))) float          f32x4;
typedef __attribute__((ext_vector_type(4))) unsigned short u16x4;
typedef __attribute__((ext_vector_type(8))) unsigned short u16x8;

#define DEV __device__ __forceinline__

static constexpr int BB   = 2;
static constexpr int SS   = 2048;
static constexpr int EMB  = 1024;
static constexpr int QKVD = 1536;   // Q(1024) | K(256) | V(256) fused output
static constexpr float SC2 = 0.18033688011112042f;  // 0.125 * log2(e)

DEV unsigned short f2b(float f) {
  union { float f; unsigned u; } v; v.f = f;
  unsigned r = (v.u + 0x7FFFu + ((v.u >> 16) & 1u)) >> 16;  // RNE
  return (unsigned short)r;
}

DEV unsigned packbf2(float a, float b) {
  __hip_bfloat162 h = __float22bfloat162_rn(make_float2(a, b));
  union { __hip_bfloat162 h; unsigned u; } c; c.h = h; return c.u;
}

DEV void gl_lds16(const void* g, void* l) {
  __builtin_amdgcn_global_load_lds((__attribute__((address_space(1))) void*)g,
                                   (__attribute__((address_space(3))) void*)l,
                                   16, 0, 0);
}

// ---------------- prep: x cast (blocks 0..2047) + weight transposes --------
__global__ __launch_bounds__(256) void prep_kernel(const float* __restrict__ x,
                                                   unsigned short* __restrict__ xb,
                                                   const float* __restrict__ Wq,
                                                   const float* __restrict__ Wk,
                                                   const float* __restrict__ Wv,
                                                   const float* __restrict__ Wo,
                                                   unsigned short* __restrict__ Wqkv_t,
                                                   unsigned short* __restrict__ Wo_t) {
  __shared__ unsigned short tile[64][72];
  const int blk = blockIdx.x;
  const int tid = threadIdx.x;
  if (blk < 2048) {
    size_t i = ((size_t)blk * 256 + tid) * 8;
    f32x4 f0 = *(const f32x4*)(x + i);
    f32x4 f1 = *(const f32x4*)(x + i + 4);
    u16x8 o;
    o[0] = f2b(f0[0]); o[1] = f2b(f0[1]); o[2] = f2b(f0[2]); o[3] = f2b(f0[3]);
    o[4] = f2b(f1[0]); o[5] = f2b(f1[1]); o[6] = f2b(f1[2]); o[7] = f2b(f1[3]);
    *(u16x8*)(xb + i) = o;
    return;
  }
  int idx = blk - 2048;
  const float* W; unsigned short* Dst; int N, kb, nb;
  if (idx < 256)      { W = Wq; Dst = Wqkv_t;                       N = 1024; kb = idx >> 4; nb = idx & 15; }
  else if (idx < 320) { int j = idx - 256; W = Wk; Dst = Wqkv_t + (size_t)1024 * 1024; N = 256; kb = j >> 2; nb = j & 3; }
  else if (idx < 384) { int j = idx - 320; W = Wv; Dst = Wqkv_t + (size_t)1280 * 1024; N = 256; kb = j >> 2; nb = j & 3; }
  else                { int j = idx - 384; W = Wo; Dst = Wo_t;      N = 1024; kb = j >> 4; nb = j & 15; }
  const int kb64 = kb * 64, nb64 = nb * 64;
#pragma unroll
  for (int p = 0; p < 16; ++p) {
    int i = tid + 256 * p;
    int k = i >> 6, n = i & 63;
    tile[k][n] = f2b(W[(size_t)(kb64 + k) * N + nb64 + n]);
  }
  __syncthreads();
#pragma unroll
  for (int p = 0; p < 16; ++p) {
    int i = tid + 256 * p;
    int n = i >> 6, k = i & 63;
    Dst[(size_t)(nb64 + n) * 1024 + kb64 + k] = tile[k][n];
  }
}

// ---------------- V^T: QKV cols [1280..1536) -> Vt[bg=b*4+g][d=64][s=2048] --
__global__ __launch_bounds__(256) void transpose_v(const unsigned short* __restrict__ QKV,
                                                   unsigned short* __restrict__ Vt) {
  __shared__ unsigned short t[64][72];
  const int s0 = blockIdx.x * 64;
  const int bg = blockIdx.y;
  const int b = bg >> 2, g = bg & 3;
  const int tid = threadIdx.x;
#pragma unroll
  for (int p = 0; p < 2; ++p) {
    int i = tid + 256 * p;
    int si = i >> 3, d0 = (i & 7) * 8;
    bf16x8 v = *(const bf16x8*)(QKV + ((size_t)(b * SS + s0 + si)) * QKVD + 1280 + g * 64 + d0);
#pragma unroll
    for (int j = 0; j < 8; ++j) t[si][d0 + j] = (unsigned short)v[j];
  }
  __syncthreads();
#pragma unroll
  for (int p = 0; p < 2; ++p) {
    int i = tid + 256 * p;
    int d = i >> 3, sv = (i & 7) * 8;
    bf16x8 vv;
#pragma unroll
    for (int j = 0; j < 8; ++j) vv[j] = (short)t[sv + j][d];
    *(bf16x8*)(Vt + ((size_t)(bg * 64 + d)) * SS + s0 + sv) = vv;
  }
}

// ---------------- GEMM: C[M,Nc] = A[M,K] * Bt[Nc,K]^T, 128x128 tile --------
// 4 waves (2x2), wave = 64x64 (4x4 frags). Counted-vmcnt double-buffer:
// stage t+2 after readers-done barrier; vmcnt(4) = previous tile resident.
template <bool BF16_OUT, bool BIAS>
__global__ __launch_bounds__(256) void gemm128(const unsigned short* __restrict__ A,
                                               const unsigned short* __restrict__ Bt,
                                               void* __restrict__ Cv,
                                               const float* __restrict__ bias,
                                               int Nc, int Kd) {
  const int tid = threadIdx.x;
  const int w = tid >> 6, lane = tid & 63;
  const int l15 = lane & 15, l4 = lane >> 4;
  const int wr = w >> 1, wc = w & 1;
  const size_t rb = (size_t)blockIdx.x * 128;
  const size_t cb = (size_t)blockIdx.y * 128;

  __shared__ alignas(16) unsigned short sA[2][128 * 32];
  __shared__ alignas(16) unsigned short sB[2][128 * 32];

  f32x4 acc[4][4] = {};

  const unsigned short* Ap = A + (rb + 32 * w + (lane >> 2)) * (size_t)Kd + (lane & 3) * 8;
  const unsigned short* Bp = Bt + (cb + 32 * w + (lane >> 2)) * (size_t)Kd + (lane & 3) * 8;

  auto STAGE = [&](int kt, int bsel) {
    const size_t off = (size_t)kt * 32;
    gl_lds16(Ap + off,                    &sA[bsel][1024 * w]);
    gl_lds16(Ap + off + 16 * (size_t)Kd, &sA[bsel][1024 * w + 512]);
    gl_lds16(Bp + off,                    &sB[bsel][1024 * w]);
    gl_lds16(Bp + off + 16 * (size_t)Kd, &sB[bsel][1024 * w + 512]);
  };

  const int KT = Kd >> 5;
  STAGE(0, 0);
  STAGE(1, 1);
  asm volatile("s_waitcnt vmcnt(4)" ::: "memory");
  __builtin_amdgcn_s_barrier();

  for (int kt = 0; kt < KT; ++kt) {
    const int cur = kt & 1;
    bf16x8 af[4], bfr[4];
#pragma unroll
    for (int m = 0; m < 4; ++m)
      af[m] = *(const bf16x8*)&sA[cur][(wr * 64 + m * 16 + l15) * 32 + 8 * l4];
#pragma unroll
    for (int n = 0; n < 4; ++n)
      bfr[n] = *(const bf16x8*)&sB[cur][(wc * 64 + n * 16 + l15) * 32 + 8 * l4];
#pragma unroll
    for (int m = 0; m < 4; ++m)
#pragma unroll
      for (int n = 0; n < 4; ++n)
        acc[m][n] = __builtin_amdgcn_mfma_f32_16x16x32_bf16(af[m], bfr[n], acc[m][n], 0, 0, 0);

    __builtin_amdgcn_s_barrier();          // all waves done reading buf[cur]
    if (kt + 2 < KT) {
      STAGE(kt + 2, cur);
      asm volatile("s_waitcnt vmcnt(4)" ::: "memory");
    } else {
      asm volatile("s_waitcnt vmcnt(0)" ::: "memory");
    }
    __builtin_amdgcn_s_barrier();          // tile kt+1 resident for everyone
  }

#pragma unroll
  for (int m = 0; m < 4; ++m)
#pragma unroll
    for (int n = 0; n < 4; ++n) {
      float bv = 0.f;
      if constexpr (BIAS) bv = bias[cb + wc * 64 + n * 16 + l15];
#pragma unroll
      for (int r = 0; r < 4; ++r) {
        size_t row = rb + wr * 64 + m * 16 + 4 * l4 + r;
        size_t col = cb + wc * 64 + n * 16 + l15;
        if constexpr (BF16_OUT)
          ((unsigned short*)Cv)[row * Nc + col] = f2b(acc[m][n][r]);
        else
          ((float*)Cv)[row * Nc + col] = acc[m][n][r] + bv;
      }
    }
}

// ---------------- flash attention -----------------------------------------
struct QS {
  bf16x8 qf0, qf1;
  f32x4 o[4];
  float m2, l;
  int qg;
};

DEV void qs_init(QS& s, const unsigned short* __restrict__ QKV,
                 int b, int h, int row0, int l15, int l4) {
  s.qg = row0 + l15;
  const unsigned short* qp =
      QKV + ((size_t)(b * SS + row0 + l15)) * QKVD + h * 64 + 8 * l4;
  s.qf0 = *(const bf16x8*)qp;
  s.qf1 = *(const bf16x8*)(qp + 32);
#pragma unroll
  for (int t = 0; t < 4; ++t) s.o[t] = f32x4{0.f, 0.f, 0.f, 0.f};
  s.m2 = -3e38f;
  s.l = 0.f;
}

DEV void qs_tile(QS& st, const unsigned short* __restrict__ sKc,
                 const unsigned short* __restrict__ sVc,
                 int kv0, bool masked,
                 int l15, int l4, int xsw, int s0, int s1, bool hi) {
  // S^T = (K Q^T): lane gets S[q=l15][kv0+16c+4*l4+r]
  f32x4 p[4];
#pragma unroll
  for (int c = 0; c < 4; ++c) {
    const unsigned short* krow = &sKc[(c * 16 + l15) * 64];
    bf16x8 kf0 = *(const bf16x8*)&krow[(l4 ^ xsw) * 8];
    bf16x8 kf1 = *(const bf16x8*)&krow[((4 | l4) ^ xsw) * 8];
    f32x4 z = {0.f, 0.f, 0.f, 0.f};
    z = __builtin_amdgcn_mfma_f32_16x16x32_bf16(kf0, st.qf0, z, 0, 0, 0);
    z = __builtin_amdgcn_mfma_f32_16x16x32_bf16(kf1, st.qf1, z, 0, 0, 0);
    p[c] = z;
  }

  if (masked) {
#pragma unroll
    for (int c = 0; c < 4; ++c)
#pragma unroll
      for (int r = 0; r < 4; ++r) {
        int kv = kv0 + c * 16 + 4 * l4 + r;
        if (kv > st.qg) p[c][r] = -3e38f;
      }
  }

  float mx = -3e38f;
#pragma unroll
  for (int c = 0; c < 4; ++c)
#pragma unroll
    for (int r = 0; r < 4; ++r) mx = fmaxf(mx, p[c][r]);
  mx = fmaxf(mx, __shfl_xor(mx, 16));
  mx = fmaxf(mx, __shfl_xor(mx, 32));
  float mx2 = mx * SC2;

  if (!__all(mx2 <= st.m2 + 8.f)) {      // defer-max (T13)
    float mn = fmaxf(st.m2, mx2);
    float corr = exp2f(st.m2 - mn);
    st.m2 = mn;
    st.l *= corr;
    f32x4 cf;
#pragma unroll
    for (int r = 0; r < 4; ++r) cf[r] = __shfl(corr, 4 * l4 + r);
#pragma unroll
    for (int t = 0; t < 4; ++t)
#pragma unroll
      for (int r = 0; r < 4; ++r) st.o[t][r] *= cf[r];
  }

  float rs = 0.f;
  unsigned w0[4], w1[4];
#pragma unroll
  for (int c = 0; c < 4; ++c) {
    float e0 = exp2f(fmaf(p[c][0], SC2, -st.m2));
    float e1 = exp2f(fmaf(p[c][1], SC2, -st.m2));
    float e2 = exp2f(fmaf(p[c][2], SC2, -st.m2));
    float e3 = exp2f(fmaf(p[c][3], SC2, -st.m2));
    rs += (e0 + e1) + (e2 + e3);
    w0[c] = packbf2(e0, e1);
    w1[c] = packbf2(e2, e3);
  }
  rs += __shfl_xor(rs, 16);
  rs += __shfl_xor(rs, 32);
  st.l += rs;

  // P relayout (dest lane (l15,l4),ks gets P[q=l15][32ks+8*l4+j]) + PV
#pragma unroll
  for (int ks = 0; ks < 2; ++ks) {
    unsigned a00 = __shfl(w0[2 * ks], s0), a01 = __shfl(w0[2 * ks + 1], s0);
    unsigned a10 = __shfl(w1[2 * ks], s0), a11 = __shfl(w1[2 * ks + 1], s0);
    unsigned b00 = __shfl(w0[2 * ks], s1), b01 = __shfl(w0[2 * ks + 1], s1);
    unsigned b10 = __shfl(w1[2 * ks], s1), b11 = __shfl(w1[2 * ks + 1], s1);
    union { bf16x8 v; unsigned u[4]; } pf;
    pf.u[0] = hi ? a01 : a00;
    pf.u[1] = hi ? a11 : a10;
    pf.u[2] = hi ? b01 : b00;
    pf.u[3] = hi ? b11 : b10;
#pragma unroll
    for (int t = 0; t < 4; ++t) {
      const unsigned short* vrow = &sVc[(t * 16 + l15) * 64];
      bf16x8 vf = *(const bf16x8*)&vrow[((4 * ks + l4) ^ xsw) * 8];
      st.o[t] = __builtin_amdgcn_mfma_f32_16x16x32_bf16(pf.v, vf, st.o[t], 0, 0, 0);
    }
  }
}

DEV void qs_write(const QS& st, unsigned short* __restrict__ Ctx,
                  int b, int h, int row0, int l15, int l4) {
  f32x4 lf;
#pragma unroll
  for (int r = 0; r < 4; ++r) lf[r] = __shfl(st.l, 4 * l4 + r);
#pragma unroll
  for (int t = 0; t < 4; ++t)
#pragma unroll
    for (int r = 0; r < 4; ++r) {
      Ctx[((size_t)(b * SS + row0 + 4 * l4 + r)) * 1024 + h * 64 + t * 16 + l15] =
          f2b(st.o[t][r] / lf[r]);
    }
}

// Block f (512): xcd=f&7, bh=xcd*4+(t5&3) (one (b,g) KV slice per XCD);
// INTRA-BLOCK complementary pair qtA=31-pairi (long), qtB=pairi (short
// prefix): every block = nkvA+nkvB = 33 tile-calls -> uniform work per
// block regardless of CU placement (round-5 lesson). Counted-vmcnt 2-deep
// pipeline with raw barriers.
__global__ __launch_bounds__(256) void attn_kernel(const unsigned short* __restrict__ QKV,
                                                   const unsigned short* __restrict__ Vt,
                                                   unsigned short* __restrict__ Ctx) {
  const int f = blockIdx.x;
  const int xcd = f & 7;
  const int t5 = (f >> 3) & 31;
  const int hi8 = f >> 8;
  const int bh = xcd * 4 + (t5 & 3);
  const int p8 = t5 >> 2;
  const int pairi = hi8 ? 15 - p8 : p8;
  const int qtA = 31 - pairi, qtB = pairi;
  const int nkvA = qtA + 1, nkvB = qtB + 1;

  const int b = bh >> 4, h = bh & 15, g = h >> 2;
  const int tid = threadIdx.x;
  const int w = tid >> 6, lane = tid & 63;
  const int l15 = lane & 15, l4 = lane >> 4;

  __shared__ alignas(16) unsigned short sK[2][64 * 64];
  __shared__ alignas(16) unsigned short sV[2][64 * 64];

  QS A, B;
  qs_init(A, QKV, b, h, qtA * 64 + w * 16, l15, l4);
  qs_init(B, QKV, b, h, qtB * 64 + w * 16, l15, l4);

  // staging: LDS[row][c] = G[row][c ^ (row&7)] (16B chunks)
  const int srow = tid >> 3;
  const int sc   = tid & 7;
  const unsigned short* kstage0 =
      QKV + ((size_t)(b * SS + srow)) * QKVD + 1024 + g * 64 + (sc ^ (srow & 7)) * 8;
  const unsigned short* kstage1 =
      QKV + ((size_t)(b * SS + srow + 32)) * QKVD + 1024 + g * 64 + (sc ^ ((srow + 32) & 7)) * 8;
  const unsigned short* vstage0 =
      Vt + ((size_t)(((b << 2) | g) * 64 + srow)) * SS + (sc ^ (srow & 7)) * 8;
  const unsigned short* vstage1 =
      Vt + ((size_t)(((b << 2) | g) * 64 + srow + 32)) * SS + (sc ^ ((srow + 32) & 7)) * 8;

  const int xsw = (l15 & 7);
  const int s0 = l15 | (((2 * l4) & 3) << 4);
  const int s1 = l15 | (((2 * l4 + 1) & 3) << 4);
  const bool hi = (l4 >= 2);

  // prologue: stage tiles 0 and 1 (nkvA >= 17 always)
  {
    char* kb0 = (char*)&sK[0][0] + (w << 10);
    char* vb0 = (char*)&sV[0][0] + (w << 10);
    gl_lds16(kstage0, kb0);
    gl_lds16(kstage1, kb0 + 4096);
    gl_lds16(vstage0, vb0);
    gl_lds16(vstage1, vb0 + 4096);
    char* kb1 = (char*)&sK[1][0] + (w << 10);
    char* vb1 = (char*)&sV[1][0] + (w << 10);
    const size_t ko = (size_t)64 * QKVD;
    gl_lds16(kstage0 + ko, kb1);
    gl_lds16(kstage1 + ko, kb1 + 4096);
    gl_lds16(vstage0 + 64, vb1);
    gl_lds16(vstage1 + 64, vb1 + 4096);
  }
  asm volatile("s_waitcnt vmcnt(4)" ::: "memory");
  __builtin_amdgcn_s_barrier();

  for (int kt = 0; kt < nkvA; ++kt) {
    const int cur = kt & 1;
    const int kv0 = kt * 64;

    qs_tile(A, &sK[cur][0], &sV[cur][0], kv0, kt == nkvA - 1, l15, l4, xsw, s0, s1, hi);
    if (kt < nkvB)
      qs_tile(B, &sK[cur][0], &sV[cur][0], kv0, kt == nkvB - 1, l15, l4, xsw, s0, s1, hi);

    __builtin_amdgcn_s_barrier();          // all waves done reading buf[cur]
    if (kt + 2 < nkvA) {
      const size_t ko = (size_t)(kv0 + 128) * QKVD;
      char* kb = (char*)&sK[cur][0] + (w << 10);
      char* vb = (char*)&sV[cur][0] + (w << 10);
      gl_lds16(kstage0 + ko, kb);
      gl_lds16(kstage1 + ko, kb + 4096);
      gl_lds16(vstage0 + kv0 + 128, vb);
      gl_lds16(vstage1 + kv0 + 128, vb + 4096);
      asm volatile("s_waitcnt vmcnt(4)" ::: "memory");
    } else {
      asm volatile("s_waitcnt vmcnt(0)" ::: "memory");
    }
    __builtin_amdgcn_s_barrier();          // tile kt+1 resident for everyone
  }

  qs_write(A, Ctx, b, h, qtA * 64 + w * 16, l15, l4);
  qs_write(B, Ctx, b, h, qtB * 64 + w * 16, l15, l4);
}

// ---------------------------------------------------------------------------
extern "C" void kernel_launch(void* const* d_in, const int* in_sizes, int n_in,
                              void* d_out, int out_size, void* d_ws, size_t ws_size,
                              hipStream_t stream) {
  (void)in_sizes; (void)n_in; (void)out_size; (void)ws_size;
  const float* x  = (const float*)d_in[0];
  const float* Wq = (const float*)d_in[1];
  const float* Wk = (const float*)d_in[2];
  const float* Wv = (const float*)d_in[3];
  const float* Wo = (const float*)d_in[4];
  const float* bo = (const float*)d_in[5];
  float* out = (float*)d_out;

  char* ws = (char*)d_ws;
  unsigned short* x_bf   = (unsigned short*)(ws);                        // 8 MiB (aliased w/ Ctx)
  unsigned short* Ctx    = (unsigned short*)(ws);                        // 8 MiB
  unsigned short* QKVb   = (unsigned short*)(ws + (size_t)( 8u << 20));  // 12 MiB
  unsigned short* Wqkv_t = (unsigned short*)(ws + (size_t)(20u << 20));  // 3 MiB
  unsigned short* Wo_t   = (unsigned short*)(ws + (size_t)(23u << 20));  // 2 MiB
  unsigned short* Vtb    = (unsigned short*)(ws + (size_t)(25u << 20));  // 2 MiB

  prep_kernel<<<dim3(2688), 256, 0, stream>>>(x, x_bf, Wq, Wk, Wv, Wo, Wqkv_t, Wo_t);

  gemm128<true, false><<<dim3(32, 12), 256, 0, stream>>>(
      x_bf, Wqkv_t, QKVb, nullptr, QKVD, EMB);

  transpose_v<<<dim3(32, 8), 256, 0, stream>>>(QKVb, Vtb);

  attn_kernel<<<dim3(512), 256, 0, stream>>>(QKVb, Vtb, Ctx);

  gemm128<false, true><<<dim3(32, 8), 256, 0, stream>>>(
      Ctx, Wo_t, out, bo, EMB, EMB);
}